// Round 10
// baseline (278.747 us; speedup 1.0000x reference)
//
#include <hip/hip_runtime.h>
#include <hip/hip_bf16.h>

// GCN 2-layer, N=50000, E=625000, feats 128->128->64. int32 edges.
// Round 10: 16 src-segments (s>>12) in the CSR buckets — concurrent gather
// window ~1.6-2.4 MB < 4 MB L2/XCD (4-segment R9 gave 152->140 MB FETCH;
// window was ~6.4 MB, too big). cursor aliases cnt (dead after scanC).
// dinv computed from off differences (tiny k_dinv). gather1 4x edge unroll
// (L2-hit latency ~200cyc -> MLP pays). Dtype runtime-detected (bf16/f32).

typedef __attribute__((ext_vector_type(8))) __bf16 bf16x8;
typedef __attribute__((ext_vector_type(8))) unsigned short ushort8;
typedef __attribute__((ext_vector_type(4))) float floatx4;

#define SEG 16
#define QSH 12   // src segment = min(src >> 12, 15); pow2, no div

static __device__ __forceinline__ float bf2f(unsigned short s) {
    unsigned u = ((unsigned)s) << 16;
    return __builtin_bit_cast(float, u);
}
static __device__ __forceinline__ unsigned short f2bf(float f) {
    unsigned u = __builtin_bit_cast(unsigned, f);
    unsigned r = (u + 0x7FFFu + ((u >> 16) & 1u)) >> 16;
    return (unsigned short)r;
}
static __device__ __forceinline__ void ld8f(const void* p, size_t idx, int isbf, float* o) {
    if (isbf) {
        ushort8 t = __builtin_bit_cast(ushort8, *(const int4*)((const unsigned short*)p + idx));
        #pragma unroll
        for (int j = 0; j < 8; ++j) o[j] = bf2f(t[j]);
    } else {
        const float* f = (const float*)p + idx;
        float4 a = *(const float4*)f;
        float4 b = *(const float4*)(f + 4);
        o[0]=a.x; o[1]=a.y; o[2]=a.z; o[3]=a.w; o[4]=b.x; o[5]=b.y; o[6]=b.z; o[7]=b.w;
    }
}
static __device__ __forceinline__ int4 ld8frag(const void* p, size_t idx, int isbf) {
    if (isbf) {
        return *(const int4*)((const unsigned short*)p + idx);
    } else {
        const float* f = (const float*)p + idx;
        float4 a = *(const float4*)f;
        float4 b = *(const float4*)(f + 4);
        ushort8 t;
        t[0]=f2bf(a.x); t[1]=f2bf(a.y); t[2]=f2bf(a.z); t[3]=f2bf(a.w);
        t[4]=f2bf(b.x); t[5]=f2bf(b.y); t[6]=f2bf(b.z); t[7]=f2bf(b.w);
        return __builtin_bit_cast(int4, t);
    }
}
static __device__ __forceinline__ float bread(const void* p, int i, int isbf) {
    return isbf ? bf2f(((const unsigned short*)p)[i]) : ((const float*)p)[i];
}

// ---------------- count (dst*SEG + src-segment) + fused dtype detect ---------
__global__ __launch_bounds__(256) void k_countdet(
    const int* __restrict__ src, const int* __restrict__ dst,
    int* __restrict__ cnt, int E, int EB,
    const unsigned* __restrict__ xw, int* __restrict__ flag)
{
    int b = blockIdx.x;
    if (b == EB) {
        __shared__ int red[256];
        int t = threadIdx.x;
        int c = 0;
        #pragma unroll
        for (int i = 0; i < 16; ++i) {
            unsigned w = xw[t * 16 + i];
            unsigned exp = (w >> 7) & 0xFFu;
            c += (exp <= 0x84u) ? 1 : 0;   // |v| < 64 as bf16
        }
        red[t] = c;
        __syncthreads();
        for (int s = 128; s > 0; s >>= 1) {
            if (t < s) red[t] += red[t + s];
            __syncthreads();
        }
        if (t == 0) flag[0] = (red[0] >= 3686) ? 1 : 0;   // >=90% of 4096
        return;
    }
    int e = b * 256 + threadIdx.x;
    if (e < E) {
        int s = src[e], d = dst[e];
        int q = s >> QSH; q = (q > SEG - 1) ? (SEG - 1) : q;
        atomicAdd(&cnt[d * SEG + q], 1);
    }
}

// ---------------- scanA: per-1024-chunk block sums over M=N*SEG --------------
__global__ __launch_bounds__(256) void k_scanA(
    const int* __restrict__ cnt, int* __restrict__ partial, int M)
{
    int b = blockIdx.x, t = threadIdx.x;
    int base = b * 1024 + t * 4;
    int s = 0;
    if (base + 3 < M) {
        int4 v = *(const int4*)&cnt[base];
        s = v.x + v.y + v.z + v.w;
    } else {
        for (int j = 0; j < 4; ++j) { int i = base + j; if (i < M) s += cnt[i]; }
    }
    #pragma unroll
    for (int d = 1; d < 64; d <<= 1) s += __shfl_down(s, d, 64);
    __shared__ int ws[4];
    int lane = t & 63, wid = t >> 6;
    if (lane == 0) ws[wid] = s;
    __syncthreads();
    if (t == 0) partial[b] = ws[0] + ws[1] + ws[2] + ws[3];
}

// ---------------- scanC: emit off + cursor (cursor may alias cnt) ------------
__global__ __launch_bounds__(256) void k_scanC(
    const int* __restrict__ cnt, const int* __restrict__ partial,
    int* __restrict__ off, int* __restrict__ cursor, int M, int nb)
{
    __shared__ int s_pref, s_tot;
    int b = blockIdx.x, t = threadIdx.x, lane = t & 63, wid = t >> 6;
    if (t == 0) {
        int s = 0, pb = 0;
        for (int i = 0; i < nb; ++i) { if (i == b) pb = s; s += partial[i]; }
        s_pref = pb; s_tot = s;
    }
    int base = b * 1024 + t * 4;
    int v[4], s = 0;
    #pragma unroll
    for (int j = 0; j < 4; ++j) {
        int i = base + j;
        v[j] = (i < M) ? cnt[i] : 0;
        s += v[j];
    }
    int x = s;
    #pragma unroll
    for (int d = 1; d < 64; d <<= 1) {
        int u = __shfl_up(x, d, 64);
        if (lane >= d) x += u;
    }
    __shared__ int wtot[4], woff[4];
    if (lane == 63) wtot[wid] = x;
    __syncthreads();
    if (t == 0) {
        int a = 0;
        #pragma unroll
        for (int w = 0; w < 4; ++w) { woff[w] = a; a += wtot[w]; }
    }
    __syncthreads();
    int excl = s_pref + woff[wid] + (x - s);
    #pragma unroll
    for (int j = 0; j < 4; ++j) {
        int i = base + j;
        if (i < M) {
            off[i] = excl;
            cursor[i] = excl;   // cursor aliases cnt: each entry read-then-written by its owner only
            excl += v[j];
        }
    }
    if (b == 0 && t == 0) off[M] = s_tot;
}

// ---------------- dinv from off differences ----------------
__global__ void k_dinv(const int* __restrict__ off, float* __restrict__ dinv, int N) {
    int i = blockIdx.x * 256 + threadIdx.x;
    if (i < N) {
        int deg = off[(i + 1) * SEG] - off[i * SEG];
        dinv[i] = rsqrtf(1.0f + (float)deg);
    }
}

// ---------------- scatter: bucket[pos] = {src, w}, keyed dst*SEG+seg ---------
__global__ void k_scatter(const int* __restrict__ src, const int* __restrict__ dst,
                          const float* __restrict__ dinv,
                          int* __restrict__ cursor, int2* __restrict__ bucket, int E) {
    int e = blockIdx.x * 256 + threadIdx.x;
    if (e >= E) return;
    int s = src[e], d = dst[e];
    int q = s >> QSH; q = (q > SEG - 1) ? (SEG - 1) : q;
    float w = dinv[s] * dinv[d];
    int pos = atomicAdd(&cursor[d * SEG + q], 1);
    int2 rec; rec.x = s; rec.y = __builtin_bit_cast(int, w);
    bucket[pos] = rec;
}

// ---------------- gather layer1: z1[d,:] = bf16( dinv_d^2*x[d] + sum w*x[s] ) --
// 16 lanes/node; edges src-segment-grouped; 4x edge unroll.
__global__ __launch_bounds__(256) void k_gather1(
    const void* __restrict__ x, const float* __restrict__ dinv,
    const int* __restrict__ off, const int2* __restrict__ bucket,
    unsigned short* __restrict__ z1, int N, const int* __restrict__ flag)
{
    int isbf = *flag;
    int gid = blockIdx.x * 256 + threadIdx.x;
    int node = gid >> 4, p = gid & 15;
    if (node >= N) return;
    float di = dinv[node];
    float acc[8], va[8], vb[8], vc[8], vd[8];
    ld8f(x, (size_t)node * 128 + p * 8, isbf, va);       // self term
    float w0 = di * di;
    #pragma unroll
    for (int j = 0; j < 8; ++j) acc[j] = w0 * va[j];
    int it = off[node * SEG], s1 = off[node * SEG + SEG];
    for (; it + 3 < s1; it += 4) {
        int2 ea = bucket[it], eb = bucket[it + 1], ec = bucket[it + 2], ed = bucket[it + 3];
        float wa = __builtin_bit_cast(float, ea.y);
        float wb = __builtin_bit_cast(float, eb.y);
        float wc = __builtin_bit_cast(float, ec.y);
        float wd = __builtin_bit_cast(float, ed.y);
        ld8f(x, (size_t)ea.x * 128 + p * 8, isbf, va);
        ld8f(x, (size_t)eb.x * 128 + p * 8, isbf, vb);
        ld8f(x, (size_t)ec.x * 128 + p * 8, isbf, vc);
        ld8f(x, (size_t)ed.x * 128 + p * 8, isbf, vd);
        #pragma unroll
        for (int j = 0; j < 8; ++j)
            acc[j] += wa * va[j] + wb * vb[j] + wc * vc[j] + wd * vd[j];
    }
    for (; it < s1; ++it) {
        int2 ea = bucket[it];
        float wa = __builtin_bit_cast(float, ea.y);
        ld8f(x, (size_t)ea.x * 128 + p * 8, isbf, va);
        #pragma unroll
        for (int j = 0; j < 8; ++j) acc[j] += wa * va[j];
    }
    ushort8 o;
    #pragma unroll
    for (int j = 0; j < 8; ++j) o[j] = f2bf(acc[j]);
    *(int4*)&z1[(size_t)node * 128 + p * 8] = __builtin_bit_cast(int4, o);
}

// ---------------- fused GEMM1+GEMM2 ----------------
__global__ __launch_bounds__(256) void k_gemm12(
    const unsigned short* __restrict__ z1, const void* __restrict__ W1,
    const void* __restrict__ b1, const void* __restrict__ W2,
    unsigned short* __restrict__ h2, int N, const int* __restrict__ flag)
{
    int isbf = *flag;
    __shared__ int4 w1f[2048];                  // 32 KB
    __shared__ unsigned short h1t[4][16 * 136]; // 17 KB
    int tid = threadIdx.x;
    for (int u = tid; u < 2048; u += 256) {
        int nt = u >> 8, kt = (u >> 6) & 3, lane = u & 63;
        int so = (nt * 16 + (lane & 15)) * 128 + kt * 32 + ((lane >> 4) << 3);
        w1f[u] = ld8frag(W1, so, isbf);
    }
    int wave = tid >> 6, lane = tid & 63, m = lane & 15, quad = lane >> 4;

    int4 w2r[4][4];
    #pragma unroll
    for (int nt = 0; nt < 4; ++nt)
        #pragma unroll
        for (int kt = 0; kt < 4; ++kt)
            w2r[nt][kt] = ld8frag(W2, (nt * 16 + m) * 128 + kt * 32 + quad * 8, isbf);
    __syncthreads();

    int ntile = (N + 15) >> 4;
    int tile = blockIdx.x * 4 + wave;
    int tcl = (tile < ntile) ? tile : (ntile - 1);   // clamp; no early return
    int arow = tcl * 16 + m;
    if (arow >= N) arow = N - 1;

    bf16x8 a[4];
    #pragma unroll
    for (int kt = 0; kt < 4; ++kt)
        a[kt] = __builtin_bit_cast(bf16x8, *(const int4*)&z1[(size_t)arow * 128 + kt * 32 + quad * 8]);
    floatx4 acc[8];
    floatx4 z = {0.f, 0.f, 0.f, 0.f};
    #pragma unroll
    for (int nt = 0; nt < 8; ++nt) acc[nt] = z;
    #pragma unroll
    for (int kt = 0; kt < 4; ++kt)
        #pragma unroll
        for (int nt = 0; nt < 8; ++nt) {
            bf16x8 b = __builtin_bit_cast(bf16x8, w1f[nt * 256 + kt * 64 + lane]);
            acc[nt] = __builtin_amdgcn_mfma_f32_16x16x32_bf16(a[kt], b, acc[nt], 0, 0, 0);
        }
    #pragma unroll
    for (int nt = 0; nt < 8; ++nt) {
        int col = nt * 16 + m;
        float bb = bread(b1, col, isbf);
        #pragma unroll
        for (int r = 0; r < 4; ++r) {
            float v = acc[nt][r] + bb;
            h1t[wave][(quad * 4 + r) * 136 + col] = f2bf(fmaxf(v, 0.f));
        }
    }
    __syncthreads();

    bf16x8 a2[4];
    #pragma unroll
    for (int kt = 0; kt < 4; ++kt)
        a2[kt] = __builtin_bit_cast(bf16x8, *(const int4*)&h1t[wave][m * 136 + kt * 32 + quad * 8]);
    floatx4 acc2[4];
    #pragma unroll
    for (int nt = 0; nt < 4; ++nt) acc2[nt] = z;
    #pragma unroll
    for (int kt = 0; kt < 4; ++kt)
        #pragma unroll
        for (int nt = 0; nt < 4; ++nt) {
            bf16x8 b = __builtin_bit_cast(bf16x8, w2r[nt][kt]);
            acc2[nt] = __builtin_amdgcn_mfma_f32_16x16x32_bf16(a2[kt], b, acc2[nt], 0, 0, 0);
        }
    if (tile < ntile) {
        int rbase = tcl * 16 + quad * 4;
        #pragma unroll
        for (int nt = 0; nt < 4; ++nt) {
            int col = nt * 16 + m;
            #pragma unroll
            for (int r = 0; r < 4; ++r) {
                int orow = rbase + r;
                if (orow < N)
                    h2[(size_t)orow * 64 + col] = f2bf(acc2[nt][r]);
            }
        }
    }
}

// ---------------- gather layer2 (dense h2, segment-grouped edges) ------------
__global__ __launch_bounds__(256) void k_gather2(
    const unsigned short* __restrict__ h2, const float* __restrict__ dinv,
    const int* __restrict__ off, const int2* __restrict__ bucket,
    const void* __restrict__ b2, void* __restrict__ out, int N,
    const int* __restrict__ flag)
{
    int isbf = *flag;
    int gid = blockIdx.x * 256 + threadIdx.x;
    int node = gid >> 3, p = gid & 7;
    if (node >= N) return;
    float di = dinv[node];
    float acc[8];
    {
        ushort8 t = __builtin_bit_cast(ushort8, *(const int4*)&h2[(size_t)node * 64 + p * 8]);
        float w0 = di * di;
        #pragma unroll
        for (int j = 0; j < 8; ++j) acc[j] = w0 * bf2f(t[j]);
    }
    int it = off[node * SEG], s1 = off[node * SEG + SEG];
    for (; it + 1 < s1; it += 2) {
        int2 ea = bucket[it], eb = bucket[it + 1];
        float wa = __builtin_bit_cast(float, ea.y);
        float wb = __builtin_bit_cast(float, eb.y);
        ushort8 ta = __builtin_bit_cast(ushort8, *(const int4*)&h2[(size_t)ea.x * 64 + p * 8]);
        ushort8 tb = __builtin_bit_cast(ushort8, *(const int4*)&h2[(size_t)eb.x * 64 + p * 8]);
        #pragma unroll
        for (int j = 0; j < 8; ++j) acc[j] += wa * bf2f(ta[j]) + wb * bf2f(tb[j]);
    }
    if (it < s1) {
        int2 ea = bucket[it];
        float wa = __builtin_bit_cast(float, ea.y);
        ushort8 ta = __builtin_bit_cast(ushort8, *(const int4*)&h2[(size_t)ea.x * 64 + p * 8]);
        #pragma unroll
        for (int j = 0; j < 8; ++j) acc[j] += wa * bf2f(ta[j]);
    }
    #pragma unroll
    for (int j = 0; j < 8; ++j) acc[j] += bread(b2, p * 8 + j, isbf);
    if (isbf) {
        ushort8 o;
        #pragma unroll
        for (int j = 0; j < 8; ++j) o[j] = f2bf(acc[j]);
        *(int4*)((unsigned short*)out + (size_t)node * 64 + p * 8) = __builtin_bit_cast(int4, o);
    } else {
        float* fo = (float*)out + (size_t)node * 64 + p * 8;
        float4 a = {acc[0], acc[1], acc[2], acc[3]};
        float4 b = {acc[4], acc[5], acc[6], acc[7]};
        *(float4*)fo = a;
        *(float4*)(fo + 4) = b;
    }
}

extern "C" void kernel_launch(void* const* d_in, const int* in_sizes, int n_in,
                              void* d_out, int out_size, void* d_ws, size_t ws_size,
                              hipStream_t stream) {
    const void* x  = d_in[0];
    const int*  ei = (const int*)d_in[1];
    const void* W1 = d_in[2];
    const void* b1 = d_in[3];
    const void* W2 = d_in[4];
    const void* b2 = d_in[5];

    int N = in_sizes[0] / 128;
    int E = in_sizes[1] / 2;
    const int* srcI = ei;
    const int* dstI = ei + E;

    int M = N * SEG;                // 800K segmented CSR entries
    int nb = (M + 1023) / 1024;     // 782
    int EB = (E + 255) / 256;       // 2442

    // ws layout (256B-aligned chunks), ~31 MB (cursor aliases cnt)
    char* base = (char*)d_ws;
    size_t o = 0;
    auto take = [&](size_t bytes) { size_t r = o; o += (bytes + 255) & ~(size_t)255; return r; };
    int*   flag    = (int*)  (base + take(4));
    int*   cnt     = (int*)  (base + take((size_t)M * 4));        // becomes cursor after scanC
    int*   off     = (int*)  (base + take((size_t)(M + 1) * 4));
    float* dinv    = (float*)(base + take((size_t)N * 4));
    int*   partial = (int*)  (base + take((size_t)nb * 4));
    int2*  bucket  = (int2*) (base + take((size_t)E * 8));
    unsigned short* z1 = (unsigned short*)(base + take((size_t)N * 128 * 2));
    unsigned short* h2 = (unsigned short*)(base + take((size_t)N * 64 * 2));
    int* cursor = cnt;   // alias: cnt dead after scanC (scanC does the handoff)

    int ntile = (N + 15) / 16;
    int gemmBlocks = (ntile + 3) / 4;

    hipMemsetAsync(cnt, 0, (size_t)M * 4, stream);
    k_countdet<<<EB + 1, 256, 0, stream>>>(srcI, dstI, cnt, E, EB, (const unsigned*)x, flag);
    k_scanA<<<nb, 256, 0, stream>>>(cnt, partial, M);
    k_scanC<<<nb, 256, 0, stream>>>(cnt, partial, off, cursor, M, nb);
    k_dinv<<<(N + 255) / 256, 256, 0, stream>>>(off, dinv, N);
    k_scatter<<<EB, 256, 0, stream>>>(srcI, dstI, dinv, cursor, bucket, E);
    k_gather1<<<(N * 16 + 255) / 256, 256, 0, stream>>>(x, dinv, off, bucket, z1, N, flag);
    k_gemm12<<<gemmBlocks, 256, 0, stream>>>(z1, W1, b1, W2, h2, N, flag);
    k_gather2<<<(N * 8 + 255) / 256, 256, 0, stream>>>(h2, dinv, off, bucket, b2, d_out, N, flag);
}

// Round 11
// 242.418 us; speedup vs baseline: 1.1499x; 1.1499x over previous
//
#include <hip/hip_runtime.h>
#include <hip/hip_bf16.h>

// GCN 2-layer, N=50000, E=625000, feats 128->128->64. int32 edges.
// Round 11: revert to R9 optimum (SEG=4 CSR segmentation, inline dinv, nb=196;
// R10's 16-seg blew up the CSR-build cost +34us with zero FETCH gain) and keep
// R10's one measured win: 4x edge unroll in gather1 (49.1->47.6us), now also
// in gather2. gather1 is at its structural floor: ~3.3 TB/s random-256B,
// FETCH ~140MB vs ~100+MB compulsory (8 XCDs x covered x-fraction).
// Wall model: sum(kernels) + ~120us fixed harness cost (verified R4->R9).
// Dtype runtime-detected (bf16 vs f32).

typedef __attribute__((ext_vector_type(8))) __bf16 bf16x8;
typedef __attribute__((ext_vector_type(8))) unsigned short ushort8;
typedef __attribute__((ext_vector_type(4))) float floatx4;

static __device__ __forceinline__ float bf2f(unsigned short s) {
    unsigned u = ((unsigned)s) << 16;
    return __builtin_bit_cast(float, u);
}
static __device__ __forceinline__ unsigned short f2bf(float f) {
    unsigned u = __builtin_bit_cast(unsigned, f);
    unsigned r = (u + 0x7FFFu + ((u >> 16) & 1u)) >> 16;
    return (unsigned short)r;
}
static __device__ __forceinline__ void ld8f(const void* p, size_t idx, int isbf, float* o) {
    if (isbf) {
        ushort8 t = __builtin_bit_cast(ushort8, *(const int4*)((const unsigned short*)p + idx));
        #pragma unroll
        for (int j = 0; j < 8; ++j) o[j] = bf2f(t[j]);
    } else {
        const float* f = (const float*)p + idx;
        float4 a = *(const float4*)f;
        float4 b = *(const float4*)(f + 4);
        o[0]=a.x; o[1]=a.y; o[2]=a.z; o[3]=a.w; o[4]=b.x; o[5]=b.y; o[6]=b.z; o[7]=b.w;
    }
}
static __device__ __forceinline__ int4 ld8frag(const void* p, size_t idx, int isbf) {
    if (isbf) {
        return *(const int4*)((const unsigned short*)p + idx);
    } else {
        const float* f = (const float*)p + idx;
        float4 a = *(const float4*)f;
        float4 b = *(const float4*)(f + 4);
        ushort8 t;
        t[0]=f2bf(a.x); t[1]=f2bf(a.y); t[2]=f2bf(a.z); t[3]=f2bf(a.w);
        t[4]=f2bf(b.x); t[5]=f2bf(b.y); t[6]=f2bf(b.z); t[7]=f2bf(b.w);
        return __builtin_bit_cast(int4, t);
    }
}
static __device__ __forceinline__ float bread(const void* p, int i, int isbf) {
    return isbf ? bf2f(((const unsigned short*)p)[i]) : ((const float*)p)[i];
}

// ---------------- count (dst*4 + src-quartile) + fused dtype detect ----------
__global__ __launch_bounds__(256) void k_countdet(
    const int* __restrict__ src, const int* __restrict__ dst,
    int* __restrict__ cnt, int E, int EB, int qdiv,
    const unsigned* __restrict__ xw, int* __restrict__ flag)
{
    int b = blockIdx.x;
    if (b == EB) {
        __shared__ int red[256];
        int t = threadIdx.x;
        int c = 0;
        #pragma unroll
        for (int i = 0; i < 16; ++i) {
            unsigned w = xw[t * 16 + i];
            unsigned exp = (w >> 7) & 0xFFu;
            c += (exp <= 0x84u) ? 1 : 0;   // |v| < 64 as bf16
        }
        red[t] = c;
        __syncthreads();
        for (int s = 128; s > 0; s >>= 1) {
            if (t < s) red[t] += red[t + s];
            __syncthreads();
        }
        if (t == 0) flag[0] = (red[0] >= 3686) ? 1 : 0;   // >=90% of 4096
        return;
    }
    int e = b * 256 + threadIdx.x;
    if (e < E) {
        int s = src[e], d = dst[e];
        int q = s / qdiv; q = (q > 3) ? 3 : q;
        atomicAdd(&cnt[d * 4 + q], 1);
    }
}

// ---------------- scanA: per-1024-chunk block sums over M=N*4 entries --------
__global__ __launch_bounds__(256) void k_scanA(
    const int* __restrict__ cnt, int* __restrict__ partial, int M)
{
    int b = blockIdx.x, t = threadIdx.x;
    int base = b * 1024 + t * 4;
    int s = 0;
    if (base + 3 < M) {
        int4 v = *(const int4*)&cnt[base];
        s = v.x + v.y + v.z + v.w;
    } else {
        for (int j = 0; j < 4; ++j) { int i = base + j; if (i < M) s += cnt[i]; }
    }
    #pragma unroll
    for (int d = 1; d < 64; d <<= 1) s += __shfl_down(s, d, 64);
    __shared__ int ws[4];
    int lane = t & 63, wid = t >> 6;
    if (lane == 0) ws[wid] = s;
    __syncthreads();
    if (t == 0) partial[b] = ws[0] + ws[1] + ws[2] + ws[3];
}

// ---------------- scanC: emit off/cursor over M entries; dinv per node -------
// Thread t of block b owns entries [b*1024+t*4 .. +3] = node (b*256+t)'s 4 quartiles.
__global__ __launch_bounds__(256) void k_scanC(
    const int* __restrict__ cnt, const int* __restrict__ partial,
    int* __restrict__ off, int* __restrict__ cursor, float* __restrict__ dinv,
    int M, int nb)
{
    __shared__ int s_pref, s_tot;
    int b = blockIdx.x, t = threadIdx.x, lane = t & 63, wid = t >> 6;
    if (t == 0) {
        int s = 0, pb = 0;
        for (int i = 0; i < nb; ++i) { if (i == b) pb = s; s += partial[i]; }
        s_pref = pb; s_tot = s;
    }
    int base = b * 1024 + t * 4;
    int v[4], s = 0;
    #pragma unroll
    for (int j = 0; j < 4; ++j) {
        int i = base + j;
        v[j] = (i < M) ? cnt[i] : 0;
        s += v[j];
    }
    int x = s;
    #pragma unroll
    for (int d = 1; d < 64; d <<= 1) {
        int u = __shfl_up(x, d, 64);
        if (lane >= d) x += u;
    }
    __shared__ int wtot[4], woff[4];
    if (lane == 63) wtot[wid] = x;
    __syncthreads();
    if (t == 0) {
        int a = 0;
        #pragma unroll
        for (int w = 0; w < 4; ++w) { woff[w] = a; a += wtot[w]; }
    }
    __syncthreads();
    int excl = s_pref + woff[wid] + (x - s);
    #pragma unroll
    for (int j = 0; j < 4; ++j) {
        int i = base + j;
        if (i < M) {
            off[i] = excl;
            cursor[i] = excl;
            excl += v[j];
        }
    }
    if (base < M) {
        int node = base >> 2;   // 4 entries per node
        dinv[node] = rsqrtf(1.0f + (float)s);   // s = node degree
    }
    if (b == 0 && t == 0) off[M] = s_tot;
}

// ---------------- scatter: bucket[pos] = {src, w}, keyed dst*4+quartile ------
__global__ void k_scatter(const int* __restrict__ src, const int* __restrict__ dst,
                          const float* __restrict__ dinv,
                          int* __restrict__ cursor, int2* __restrict__ bucket,
                          int E, int qdiv) {
    int e = blockIdx.x * 256 + threadIdx.x;
    if (e >= E) return;
    int s = src[e], d = dst[e];
    int q = s / qdiv; q = (q > 3) ? 3 : q;
    float w = dinv[s] * dinv[d];
    int pos = atomicAdd(&cursor[d * 4 + q], 1);
    int2 rec; rec.x = s; rec.y = __builtin_bit_cast(int, w);
    bucket[pos] = rec;
}

// ---------------- gather layer1: z1[d,:] = bf16( dinv_d^2*x[d] + sum w*x[s] ) --
// 16 lanes/node; edges src-quartile-grouped; 4x edge unroll.
__global__ __launch_bounds__(256) void k_gather1(
    const void* __restrict__ x, const float* __restrict__ dinv,
    const int* __restrict__ off, const int2* __restrict__ bucket,
    unsigned short* __restrict__ z1, int N, const int* __restrict__ flag)
{
    int isbf = *flag;
    int gid = blockIdx.x * 256 + threadIdx.x;
    int node = gid >> 4, p = gid & 15;
    if (node >= N) return;
    float di = dinv[node];
    float acc[8], va[8], vb[8], vc[8], vd[8];
    ld8f(x, (size_t)node * 128 + p * 8, isbf, va);       // self term
    float w0 = di * di;
    #pragma unroll
    for (int j = 0; j < 8; ++j) acc[j] = w0 * va[j];
    int it = off[node * 4], s1 = off[node * 4 + 4];
    for (; it + 3 < s1; it += 4) {
        int2 ea = bucket[it], eb = bucket[it + 1], ec = bucket[it + 2], ed = bucket[it + 3];
        float wa = __builtin_bit_cast(float, ea.y);
        float wb = __builtin_bit_cast(float, eb.y);
        float wc = __builtin_bit_cast(float, ec.y);
        float wd = __builtin_bit_cast(float, ed.y);
        ld8f(x, (size_t)ea.x * 128 + p * 8, isbf, va);
        ld8f(x, (size_t)eb.x * 128 + p * 8, isbf, vb);
        ld8f(x, (size_t)ec.x * 128 + p * 8, isbf, vc);
        ld8f(x, (size_t)ed.x * 128 + p * 8, isbf, vd);
        #pragma unroll
        for (int j = 0; j < 8; ++j)
            acc[j] += wa * va[j] + wb * vb[j] + wc * vc[j] + wd * vd[j];
    }
    for (; it < s1; ++it) {
        int2 ea = bucket[it];
        float wa = __builtin_bit_cast(float, ea.y);
        ld8f(x, (size_t)ea.x * 128 + p * 8, isbf, va);
        #pragma unroll
        for (int j = 0; j < 8; ++j) acc[j] += wa * va[j];
    }
    ushort8 o;
    #pragma unroll
    for (int j = 0; j < 8; ++j) o[j] = f2bf(acc[j]);
    *(int4*)&z1[(size_t)node * 128 + p * 8] = __builtin_bit_cast(int4, o);
}

// ---------------- fused GEMM1+GEMM2 ----------------
__global__ __launch_bounds__(256) void k_gemm12(
    const unsigned short* __restrict__ z1, const void* __restrict__ W1,
    const void* __restrict__ b1, const void* __restrict__ W2,
    unsigned short* __restrict__ h2, int N, const int* __restrict__ flag)
{
    int isbf = *flag;
    __shared__ int4 w1f[2048];                  // 32 KB
    __shared__ unsigned short h1t[4][16 * 136]; // 17 KB
    int tid = threadIdx.x;
    for (int u = tid; u < 2048; u += 256) {
        int nt = u >> 8, kt = (u >> 6) & 3, lane = u & 63;
        int so = (nt * 16 + (lane & 15)) * 128 + kt * 32 + ((lane >> 4) << 3);
        w1f[u] = ld8frag(W1, so, isbf);
    }
    int wave = tid >> 6, lane = tid & 63, m = lane & 15, quad = lane >> 4;

    int4 w2r[4][4];
    #pragma unroll
    for (int nt = 0; nt < 4; ++nt)
        #pragma unroll
        for (int kt = 0; kt < 4; ++kt)
            w2r[nt][kt] = ld8frag(W2, (nt * 16 + m) * 128 + kt * 32 + quad * 8, isbf);
    __syncthreads();

    int ntile = (N + 15) >> 4;
    int tile = blockIdx.x * 4 + wave;
    int tcl = (tile < ntile) ? tile : (ntile - 1);   // clamp; no early return
    int arow = tcl * 16 + m;
    if (arow >= N) arow = N - 1;

    bf16x8 a[4];
    #pragma unroll
    for (int kt = 0; kt < 4; ++kt)
        a[kt] = __builtin_bit_cast(bf16x8, *(const int4*)&z1[(size_t)arow * 128 + kt * 32 + quad * 8]);
    floatx4 acc[8];
    floatx4 z = {0.f, 0.f, 0.f, 0.f};
    #pragma unroll
    for (int nt = 0; nt < 8; ++nt) acc[nt] = z;
    #pragma unroll
    for (int kt = 0; kt < 4; ++kt)
        #pragma unroll
        for (int nt = 0; nt < 8; ++nt) {
            bf16x8 b = __builtin_bit_cast(bf16x8, w1f[nt * 256 + kt * 64 + lane]);
            acc[nt] = __builtin_amdgcn_mfma_f32_16x16x32_bf16(a[kt], b, acc[nt], 0, 0, 0);
        }
    #pragma unroll
    for (int nt = 0; nt < 8; ++nt) {
        int col = nt * 16 + m;
        float bb = bread(b1, col, isbf);
        #pragma unroll
        for (int r = 0; r < 4; ++r) {
            float v = acc[nt][r] + bb;
            h1t[wave][(quad * 4 + r) * 136 + col] = f2bf(fmaxf(v, 0.f));
        }
    }
    __syncthreads();

    bf16x8 a2[4];
    #pragma unroll
    for (int kt = 0; kt < 4; ++kt)
        a2[kt] = __builtin_bit_cast(bf16x8, *(const int4*)&h1t[wave][m * 136 + kt * 32 + quad * 8]);
    floatx4 acc2[4];
    #pragma unroll
    for (int nt = 0; nt < 4; ++nt) acc2[nt] = z;
    #pragma unroll
    for (int kt = 0; kt < 4; ++kt)
        #pragma unroll
        for (int nt = 0; nt < 4; ++nt) {
            bf16x8 b = __builtin_bit_cast(bf16x8, w2r[nt][kt]);
            acc2[nt] = __builtin_amdgcn_mfma_f32_16x16x32_bf16(a2[kt], b, acc2[nt], 0, 0, 0);
        }
    if (tile < ntile) {
        int rbase = tcl * 16 + quad * 4;
        #pragma unroll
        for (int nt = 0; nt < 4; ++nt) {
            int col = nt * 16 + m;
            #pragma unroll
            for (int r = 0; r < 4; ++r) {
                int orow = rbase + r;
                if (orow < N)
                    h2[(size_t)orow * 64 + col] = f2bf(acc2[nt][r]);
            }
        }
    }
}

// ---------------- gather layer2 (dense h2, quartile-grouped, 4x unroll) ------
__global__ __launch_bounds__(256) void k_gather2(
    const unsigned short* __restrict__ h2, const float* __restrict__ dinv,
    const int* __restrict__ off, const int2* __restrict__ bucket,
    const void* __restrict__ b2, void* __restrict__ out, int N,
    const int* __restrict__ flag)
{
    int isbf = *flag;
    int gid = blockIdx.x * 256 + threadIdx.x;
    int node = gid >> 3, p = gid & 7;
    if (node >= N) return;
    float di = dinv[node];
    float acc[8];
    {
        ushort8 t = __builtin_bit_cast(ushort8, *(const int4*)&h2[(size_t)node * 64 + p * 8]);
        float w0 = di * di;
        #pragma unroll
        for (int j = 0; j < 8; ++j) acc[j] = w0 * bf2f(t[j]);
    }
    int it = off[node * 4], s1 = off[node * 4 + 4];
    for (; it + 3 < s1; it += 4) {
        int2 ea = bucket[it], eb = bucket[it + 1], ec = bucket[it + 2], ed = bucket[it + 3];
        float wa = __builtin_bit_cast(float, ea.y);
        float wb = __builtin_bit_cast(float, eb.y);
        float wc = __builtin_bit_cast(float, ec.y);
        float wd = __builtin_bit_cast(float, ed.y);
        ushort8 ta = __builtin_bit_cast(ushort8, *(const int4*)&h2[(size_t)ea.x * 64 + p * 8]);
        ushort8 tb = __builtin_bit_cast(ushort8, *(const int4*)&h2[(size_t)eb.x * 64 + p * 8]);
        ushort8 tc = __builtin_bit_cast(ushort8, *(const int4*)&h2[(size_t)ec.x * 64 + p * 8]);
        ushort8 td = __builtin_bit_cast(ushort8, *(const int4*)&h2[(size_t)ed.x * 64 + p * 8]);
        #pragma unroll
        for (int j = 0; j < 8; ++j)
            acc[j] += wa * bf2f(ta[j]) + wb * bf2f(tb[j]) + wc * bf2f(tc[j]) + wd * bf2f(td[j]);
    }
    for (; it < s1; ++it) {
        int2 ea = bucket[it];
        float wa = __builtin_bit_cast(float, ea.y);
        ushort8 ta = __builtin_bit_cast(ushort8, *(const int4*)&h2[(size_t)ea.x * 64 + p * 8]);
        #pragma unroll
        for (int j = 0; j < 8; ++j) acc[j] += wa * bf2f(ta[j]);
    }
    #pragma unroll
    for (int j = 0; j < 8; ++j) acc[j] += bread(b2, p * 8 + j, isbf);
    if (isbf) {
        ushort8 o;
        #pragma unroll
        for (int j = 0; j < 8; ++j) o[j] = f2bf(acc[j]);
        *(int4*)((unsigned short*)out + (size_t)node * 64 + p * 8) = __builtin_bit_cast(int4, o);
    } else {
        float* fo = (float*)out + (size_t)node * 64 + p * 8;
        float4 a = {acc[0], acc[1], acc[2], acc[3]};
        float4 b = {acc[4], acc[5], acc[6], acc[7]};
        *(float4*)fo = a;
        *(float4*)(fo + 4) = b;
    }
}

extern "C" void kernel_launch(void* const* d_in, const int* in_sizes, int n_in,
                              void* d_out, int out_size, void* d_ws, size_t ws_size,
                              hipStream_t stream) {
    const void* x  = d_in[0];
    const int*  ei = (const int*)d_in[1];
    const void* W1 = d_in[2];
    const void* b1 = d_in[3];
    const void* W2 = d_in[4];
    const void* b2 = d_in[5];

    int N = in_sizes[0] / 128;
    int E = in_sizes[1] / 2;
    const int* srcI = ei;
    const int* dstI = ei + E;

    int M = N * 4;                  // segmented CSR entries
    int qdiv = (N + 3) / 4;         // 12500
    int nb = (M + 1023) / 1024;     // 196
    int EB = (E + 255) / 256;       // 2442

    // ws layout (256B-aligned chunks), ~26.8 MB total
    char* base = (char*)d_ws;
    size_t o = 0;
    auto take = [&](size_t bytes) { size_t r = o; o += (bytes + 255) & ~(size_t)255; return r; };
    int*   flag    = (int*)  (base + take(4));
    int*   cnt     = (int*)  (base + take((size_t)M * 4));
    int*   off     = (int*)  (base + take((size_t)(M + 1) * 4));
    int*   cursor  = (int*)  (base + take((size_t)M * 4));
    float* dinv    = (float*)(base + take((size_t)N * 4));
    int*   partial = (int*)  (base + take((size_t)nb * 4));
    int2*  bucket  = (int2*) (base + take((size_t)E * 8));
    unsigned short* z1 = (unsigned short*)(base + take((size_t)N * 128 * 2));
    unsigned short* h2 = (unsigned short*)(base + take((size_t)N * 64 * 2));

    int ntile = (N + 15) / 16;
    int gemmBlocks = (ntile + 3) / 4;

    hipMemsetAsync(cnt, 0, (size_t)M * 4, stream);
    k_countdet<<<EB + 1, 256, 0, stream>>>(srcI, dstI, cnt, E, EB, qdiv, (const unsigned*)x, flag);
    k_scanA<<<nb, 256, 0, stream>>>(cnt, partial, M);
    k_scanC<<<nb, 256, 0, stream>>>(cnt, partial, off, cursor, dinv, M, nb);
    k_scatter<<<EB, 256, 0, stream>>>(srcI, dstI, dinv, cursor, bucket, E, qdiv);
    k_gather1<<<(N * 16 + 255) / 256, 256, 0, stream>>>(x, dinv, off, bucket, z1, N, flag);
    k_gemm12<<<gemmBlocks, 256, 0, stream>>>(z1, W1, b1, W2, h2, N, flag);
    k_gather2<<<(N * 8 + 255) / 256, 256, 0, stream>>>(h2, dinv, off, bucket, b2, d_out, N, flag);
}